// Round 1
// baseline (2991.247 us; speedup 1.0000x reference)
//
#include <hip/hip_runtime.h>

// DynamicFilter fused kernel (fp32, vector ALU).
// Pipeline per 32x32 output tile (one block, 256 threads):
//   1. Load x halo (2ch, 40x40, zero-filled OOB) into LDS.
//   2. 16 phases x 2 channels:
//        conv1 5x5 (2->ch) + bias + LeakyReLU on 36x36 halo -> LDS hs
//        (h forced to 0 outside global bounds == conv2 zero-padding)
//        conv2 5x5 accumulate into 9 filter accs x 4 px per thread,
//        weights as scalar (uniform) operands, h rows via ds_read_b128.
//   3. Epilogue: out = sum_f image[y+fy-1][x+fx-1] * (acc[f]+b2[f]), float4 store.

#define HH 512
#define WW 512
#define TILE 32
#define XS_H 40
#define XS_W 40
#define HS_H 36
#define HS_W 40   // padded row stride, keeps 16B alignment for b128 reads

__global__ __launch_bounds__(256, 4)
void dynfilt_fused(const float* __restrict__ image,
                   const float* __restrict__ refer,
                   const float* __restrict__ w1,
                   const float* __restrict__ b1,
                   const float* __restrict__ w2,
                   const float* __restrict__ b2,
                   float* __restrict__ out)
{
    __shared__ float xs[2][XS_H][XS_W];
    __shared__ float hs[2][HS_H][HS_W];

    const int t  = threadIdx.x;
    const int gx0 = blockIdx.x * TILE;
    const int gy0 = blockIdx.y * TILE;
    const int b   = blockIdx.z;

    // ---- stage x halo: rows gy0-4..gy0+35, cols gx0-4..gx0+35, 2 channels ----
    for (int idx = t; idx < 2 * XS_H * XS_W; idx += 256) {
        int ci  = idx / (XS_H * XS_W);
        int rem = idx - ci * (XS_H * XS_W);
        int r   = rem / XS_W;
        int c   = rem - r * XS_W;
        int gy  = gy0 - 4 + r;
        int gx  = gx0 - 4 + c;
        float v = 0.f;
        if (gy >= 0 && gy < HH && gx >= 0 && gx < WW) {
            const float* src = ci ? refer : image;
            v = src[((size_t)b * HH + gy) * WW + gx];
        }
        (&xs[0][0][0])[idx] = v;
    }

    // per-thread output pixels: row ly, cols lx0..lx0+3
    const int ly  = t >> 3;
    const int lx0 = (t & 7) << 2;

    // conv1 strip mapping: 216 slots, each computes 2 rows x 3 cols of h
    const int rp = t / 12;        // row pair 0..17
    const int cg = t - rp * 12;   // col group 0..11
    const int r0 = rp * 2;
    const int c0 = cg * 3;

    float acc[9][4];
    #pragma unroll
    for (int f = 0; f < 9; ++f)
        #pragma unroll
        for (int p = 0; p < 4; ++p)
            acc[f][p] = 0.f;

    #pragma unroll 1
    for (int ph = 0; ph < 16; ++ph) {
        __syncthreads();   // prev conv2 done reading hs (and xs load on ph=0)

        // ---- conv1: channels 2ph, 2ph+1 into hs[0], hs[1] ----
        if (t < 216) {
            #pragma unroll 1
            for (int cc = 0; cc < 2; ++cc) {
                const int ch = ph * 2 + cc;
                float a[2][3] = {{0.f,0.f,0.f},{0.f,0.f,0.f}};
                #pragma unroll
                for (int ci = 0; ci < 2; ++ci) {
                    const float* wp = w1 + (ch * 2 + ci) * 25;
                    #pragma unroll
                    for (int wy = 0; wy < 6; ++wy) {
                        float rv[7];
                        #pragma unroll
                        for (int j = 0; j < 7; ++j)
                            rv[j] = xs[ci][r0 + wy][c0 + j];
                        if (wy < 5) {
                            #pragma unroll
                            for (int dx = 0; dx < 5; ++dx) {
                                float wv = wp[wy * 5 + dx];
                                #pragma unroll
                                for (int j = 0; j < 3; ++j)
                                    a[0][j] += rv[j + dx] * wv;
                            }
                        }
                        if (wy >= 1) {
                            #pragma unroll
                            for (int dx = 0; dx < 5; ++dx) {
                                float wv = wp[(wy - 1) * 5 + dx];
                                #pragma unroll
                                for (int j = 0; j < 3; ++j)
                                    a[1][j] += rv[j + dx] * wv;
                            }
                        }
                    }
                }
                float bias = b1[ch];
                #pragma unroll
                for (int i = 0; i < 2; ++i) {
                    int hy = r0 + i;
                    int gy = gy0 + hy - 2;
                    #pragma unroll
                    for (int j = 0; j < 3; ++j) {
                        int hx = c0 + j;
                        int gx = gx0 + hx - 2;
                        float v = a[i][j] + bias;
                        v = (v >= 0.f) ? v : 0.1f * v;
                        if (gy < 0 || gy >= HH || gx < 0 || gx >= WW) v = 0.f;
                        hs[cc][hy][hx] = v;
                    }
                }
            }
        }

        __syncthreads();   // hs ready

        // ---- conv2 accumulate ----
        #pragma unroll 1
        for (int cc = 0; cc < 2; ++cc) {
            const int ch = ph * 2 + cc;
            #pragma unroll
            for (int dy = 0; dy < 5; ++dy) {
                const float4* hp = (const float4*)&hs[cc][ly + dy][lx0];
                float4 ha = hp[0];
                float4 hb = hp[1];
                float hreg[8] = {ha.x, ha.y, ha.z, ha.w, hb.x, hb.y, hb.z, hb.w};
                #pragma unroll
                for (int f = 0; f < 9; ++f) {
                    const float* wp = w2 + (f * 32 + ch) * 25 + dy * 5;
                    #pragma unroll
                    for (int dx = 0; dx < 5; ++dx) {
                        float wv = wp[dx];
                        #pragma unroll
                        for (int p = 0; p < 4; ++p)
                            acc[f][p] += hreg[p + dx] * wv;
                    }
                }
            }
        }
    }

    // ---- epilogue: im2col(3x3, pad=1) dot; xs OOB entries are already 0 ----
    float res[4] = {0.f, 0.f, 0.f, 0.f};
    #pragma unroll
    for (int fy = 0; fy < 3; ++fy) {
        #pragma unroll
        for (int fx = 0; fx < 3; ++fx) {
            int f = fy * 3 + fx;
            float bf = b2[f];
            #pragma unroll
            for (int p = 0; p < 4; ++p) {
                float e = xs[0][ly + fy + 3][lx0 + p + fx + 3];
                res[p] += e * (acc[f][p] + bf);
            }
        }
    }

    size_t o = ((size_t)b * HH + (gy0 + ly)) * WW + gx0 + lx0;
    float4 ov = make_float4(res[0], res[1], res[2], res[3]);
    *(float4*)(out + o) = ov;
}

extern "C" void kernel_launch(void* const* d_in, const int* in_sizes, int n_in,
                              void* d_out, int out_size, void* d_ws, size_t ws_size,
                              hipStream_t stream) {
    const float* image = (const float*)d_in[0];
    const float* refer = (const float*)d_in[1];
    const float* w1    = (const float*)d_in[2];
    const float* b1    = (const float*)d_in[3];
    const float* w2    = (const float*)d_in[4];
    const float* b2    = (const float*)d_in[5];
    float* out = (float*)d_out;

    dim3 grid(WW / TILE, HH / TILE, 8);
    dim3 block(256);
    hipLaunchKernelGGL(dynfilt_fused, grid, block, 0, stream,
                       image, refer, w1, b1, w2, b2, out);
}

// Round 2
// 1742.779 us; speedup vs baseline: 1.7164x; 1.7164x over previous
//
#include <hip/hip_runtime.h>

// DynamicFilter fused kernel (fp32, vector ALU).
// R2 change: __launch_bounds__(256,4) -> (256,2). R1 spilled the 36-float
// accumulator set to scratch (VGPR_Count=64, 10.8 GB symmetric HBM traffic,
// VALUBusy 11%). 256-VGPR cap keeps acc[9][4] + conv windows in registers.
//
// Pipeline per 32x32 output tile (one block, 256 threads):
//   1. Load x halo (2ch, 40x40, zero-filled OOB) into LDS.
//   2. 16 phases x 2 channels:
//        conv1 5x5 (2->ch) + bias + LeakyReLU on 36x36 halo -> LDS hs
//        (h forced to 0 outside global bounds == conv2 zero-padding)
//        conv2 5x5 accumulate into 9 filter accs x 4 px per thread,
//        weights as scalar (uniform) operands, h rows via ds_read_b128.
//   3. Epilogue: out = sum_f image[y+fy-1][x+fx-1] * (acc[f]+b2[f]), float4 store.

#define HH 512
#define WW 512
#define TILE 32
#define XS_H 40
#define XS_W 40
#define HS_H 36
#define HS_W 40   // padded row stride, keeps 16B alignment for b128 reads

__global__ __launch_bounds__(256, 2)
void dynfilt_fused(const float* __restrict__ image,
                   const float* __restrict__ refer,
                   const float* __restrict__ w1,
                   const float* __restrict__ b1,
                   const float* __restrict__ w2,
                   const float* __restrict__ b2,
                   float* __restrict__ out)
{
    __shared__ float xs[2][XS_H][XS_W];
    __shared__ float hs[2][HS_H][HS_W];

    const int t  = threadIdx.x;
    const int gx0 = blockIdx.x * TILE;
    const int gy0 = blockIdx.y * TILE;
    const int b   = blockIdx.z;

    // ---- stage x halo: rows gy0-4..gy0+35, cols gx0-4..gx0+35, 2 channels ----
    for (int idx = t; idx < 2 * XS_H * XS_W; idx += 256) {
        int ci  = idx / (XS_H * XS_W);
        int rem = idx - ci * (XS_H * XS_W);
        int r   = rem / XS_W;
        int c   = rem - r * XS_W;
        int gy  = gy0 - 4 + r;
        int gx  = gx0 - 4 + c;
        float v = 0.f;
        if (gy >= 0 && gy < HH && gx >= 0 && gx < WW) {
            const float* src = ci ? refer : image;
            v = src[((size_t)b * HH + gy) * WW + gx];
        }
        (&xs[0][0][0])[idx] = v;
    }

    // per-thread output pixels: row ly, cols lx0..lx0+3
    const int ly  = t >> 3;
    const int lx0 = (t & 7) << 2;

    // conv1 strip mapping: 216 slots, each computes 2 rows x 3 cols of h
    const int rp = t / 12;        // row pair 0..17
    const int cg = t - rp * 12;   // col group 0..11
    const int r0 = rp * 2;
    const int c0 = cg * 3;

    float acc[9][4];
    #pragma unroll
    for (int f = 0; f < 9; ++f)
        #pragma unroll
        for (int p = 0; p < 4; ++p)
            acc[f][p] = 0.f;

    #pragma unroll 1
    for (int ph = 0; ph < 16; ++ph) {
        __syncthreads();   // prev conv2 done reading hs (and xs load on ph=0)

        // ---- conv1: channels 2ph, 2ph+1 into hs[0], hs[1] ----
        if (t < 216) {
            #pragma unroll 1
            for (int cc = 0; cc < 2; ++cc) {
                const int ch = ph * 2 + cc;
                float a[2][3] = {{0.f,0.f,0.f},{0.f,0.f,0.f}};
                #pragma unroll
                for (int ci = 0; ci < 2; ++ci) {
                    const float* wp = w1 + (ch * 2 + ci) * 25;
                    #pragma unroll
                    for (int wy = 0; wy < 6; ++wy) {
                        float rv[7];
                        #pragma unroll
                        for (int j = 0; j < 7; ++j)
                            rv[j] = xs[ci][r0 + wy][c0 + j];
                        if (wy < 5) {
                            #pragma unroll
                            for (int dx = 0; dx < 5; ++dx) {
                                float wv = wp[wy * 5 + dx];
                                #pragma unroll
                                for (int j = 0; j < 3; ++j)
                                    a[0][j] += rv[j + dx] * wv;
                            }
                        }
                        if (wy >= 1) {
                            #pragma unroll
                            for (int dx = 0; dx < 5; ++dx) {
                                float wv = wp[(wy - 1) * 5 + dx];
                                #pragma unroll
                                for (int j = 0; j < 3; ++j)
                                    a[1][j] += rv[j + dx] * wv;
                            }
                        }
                    }
                }
                float bias = b1[ch];
                #pragma unroll
                for (int i = 0; i < 2; ++i) {
                    int hy = r0 + i;
                    int gy = gy0 + hy - 2;
                    #pragma unroll
                    for (int j = 0; j < 3; ++j) {
                        int hx = c0 + j;
                        int gx = gx0 + hx - 2;
                        float v = a[i][j] + bias;
                        v = (v >= 0.f) ? v : 0.1f * v;
                        if (gy < 0 || gy >= HH || gx < 0 || gx >= WW) v = 0.f;
                        hs[cc][hy][hx] = v;
                    }
                }
            }
        }

        __syncthreads();   // hs ready

        // ---- conv2 accumulate ----
        #pragma unroll 1
        for (int cc = 0; cc < 2; ++cc) {
            const int ch = ph * 2 + cc;
            #pragma unroll
            for (int dy = 0; dy < 5; ++dy) {
                const float4* hp = (const float4*)&hs[cc][ly + dy][lx0];
                float4 ha = hp[0];
                float4 hb = hp[1];
                float hreg[8] = {ha.x, ha.y, ha.z, ha.w, hb.x, hb.y, hb.z, hb.w};
                #pragma unroll
                for (int f = 0; f < 9; ++f) {
                    const float* wp = w2 + (f * 32 + ch) * 25 + dy * 5;
                    #pragma unroll
                    for (int dx = 0; dx < 5; ++dx) {
                        float wv = wp[dx];
                        #pragma unroll
                        for (int p = 0; p < 4; ++p)
                            acc[f][p] += hreg[p + dx] * wv;
                    }
                }
            }
        }
    }

    // ---- epilogue: im2col(3x3, pad=1) dot; xs OOB entries are already 0 ----
    float res[4] = {0.f, 0.f, 0.f, 0.f};
    #pragma unroll
    for (int fy = 0; fy < 3; ++fy) {
        #pragma unroll
        for (int fx = 0; fx < 3; ++fx) {
            int f = fy * 3 + fx;
            float bf = b2[f];
            #pragma unroll
            for (int p = 0; p < 4; ++p) {
                float e = xs[0][ly + fy + 3][lx0 + p + fx + 3];
                res[p] += e * (acc[f][p] + bf);
            }
        }
    }

    size_t o = ((size_t)b * HH + (gy0 + ly)) * WW + gx0 + lx0;
    float4 ov = make_float4(res[0], res[1], res[2], res[3]);
    *(float4*)(out + o) = ov;
}

extern "C" void kernel_launch(void* const* d_in, const int* in_sizes, int n_in,
                              void* d_out, int out_size, void* d_ws, size_t ws_size,
                              hipStream_t stream) {
    const float* image = (const float*)d_in[0];
    const float* refer = (const float*)d_in[1];
    const float* w1    = (const float*)d_in[2];
    const float* b1    = (const float*)d_in[3];
    const float* w2    = (const float*)d_in[4];
    const float* b2    = (const float*)d_in[5];
    float* out = (float*)d_out;

    dim3 grid(WW / TILE, HH / TILE, 8);
    dim3 block(256);
    hipLaunchKernelGGL(dynfilt_fused, grid, block, 0, stream,
                       image, refer, w1, b1, w2, b2, out);
}

// Round 3
// 1288.126 us; speedup vs baseline: 2.3222x; 1.3530x over previous
//
#include <hip/hip_runtime.h>

// DynamicFilter fused kernel (fp32, vector ALU).
// R3 change: force amdgpu_waves_per_eu(2,2). R2 showed the allocator snapping
// to the 128-VGPR / 4-waves-per-SIMD boundary and spilling ~3.4 KB/thread
// (WRITE_SIZE 1.79 GB vs 8.4 MB ideal). min=max=2 gives a 256-VGPR budget so
// acc[9][4] + conv working set stay in registers. 8 waves/CU is enough for a
// VALU-bound kernel with 36 independent accumulator chains.
//
// Pipeline per 32x32 output tile (one block, 256 threads):
//   1. Load x halo (2ch, 40x40, zero-filled OOB) into LDS.
//   2. 16 phases x 2 channels:
//        conv1 5x5 (2->ch) + bias + LeakyReLU on 36x36 halo -> LDS hs
//        (h forced to 0 outside global bounds == conv2 zero-padding)
//        conv2 5x5 accumulate into 9 filter accs x 4 px per thread.
//   3. Epilogue: out = sum_f image[y+fy-1][x+fx-1] * (acc[f]+b2[f]), float4 store.

#define HH 512
#define WW 512
#define TILE 32
#define XS_H 40
#define XS_W 40
#define HS_H 36
#define HS_W 40   // padded row stride, keeps 16B alignment for b128 reads

__global__
__attribute__((amdgpu_flat_work_group_size(256, 256), amdgpu_waves_per_eu(2, 2)))
void dynfilt_fused(const float* __restrict__ image,
                   const float* __restrict__ refer,
                   const float* __restrict__ w1,
                   const float* __restrict__ b1,
                   const float* __restrict__ w2,
                   const float* __restrict__ b2,
                   float* __restrict__ out)
{
    __shared__ float xs[2][XS_H][XS_W];
    __shared__ float hs[2][HS_H][HS_W];

    const int t  = threadIdx.x;
    const int gx0 = blockIdx.x * TILE;
    const int gy0 = blockIdx.y * TILE;
    const int b   = blockIdx.z;

    // ---- stage x halo: rows gy0-4..gy0+35, cols gx0-4..gx0+35, 2 channels ----
    for (int idx = t; idx < 2 * XS_H * XS_W; idx += 256) {
        int ci  = idx / (XS_H * XS_W);
        int rem = idx - ci * (XS_H * XS_W);
        int r   = rem / XS_W;
        int c   = rem - r * XS_W;
        int gy  = gy0 - 4 + r;
        int gx  = gx0 - 4 + c;
        float v = 0.f;
        if (gy >= 0 && gy < HH && gx >= 0 && gx < WW) {
            const float* src = ci ? refer : image;
            v = src[((size_t)b * HH + gy) * WW + gx];
        }
        (&xs[0][0][0])[idx] = v;
    }

    // per-thread output pixels: row ly, cols lx0..lx0+3
    const int ly  = t >> 3;
    const int lx0 = (t & 7) << 2;

    // conv1 strip mapping: 216 slots, each computes 2 rows x 3 cols of h
    const int rp = t / 12;        // row pair 0..17
    const int cg = t - rp * 12;   // col group 0..11
    const int r0 = rp * 2;
    const int c0 = cg * 3;

    float acc[9][4];
    #pragma unroll
    for (int f = 0; f < 9; ++f)
        #pragma unroll
        for (int p = 0; p < 4; ++p)
            acc[f][p] = 0.f;

    #pragma unroll 1
    for (int ph = 0; ph < 16; ++ph) {
        __syncthreads();   // prev conv2 done reading hs (and xs load on ph=0)

        // ---- conv1: channels 2ph, 2ph+1 into hs[0], hs[1] ----
        if (t < 216) {
            #pragma unroll 1
            for (int cc = 0; cc < 2; ++cc) {
                const int ch = ph * 2 + cc;
                float a[2][3] = {{0.f,0.f,0.f},{0.f,0.f,0.f}};
                #pragma unroll
                for (int ci = 0; ci < 2; ++ci) {
                    const float* wp = w1 + (ch * 2 + ci) * 25;
                    #pragma unroll
                    for (int wy = 0; wy < 6; ++wy) {
                        float rv[7];
                        #pragma unroll
                        for (int j = 0; j < 7; ++j)
                            rv[j] = xs[ci][r0 + wy][c0 + j];
                        if (wy < 5) {
                            #pragma unroll
                            for (int dx = 0; dx < 5; ++dx) {
                                float wv = wp[wy * 5 + dx];
                                #pragma unroll
                                for (int j = 0; j < 3; ++j)
                                    a[0][j] += rv[j + dx] * wv;
                            }
                        }
                        if (wy >= 1) {
                            #pragma unroll
                            for (int dx = 0; dx < 5; ++dx) {
                                float wv = wp[(wy - 1) * 5 + dx];
                                #pragma unroll
                                for (int j = 0; j < 3; ++j)
                                    a[1][j] += rv[j + dx] * wv;
                            }
                        }
                    }
                }
                float bias = b1[ch];
                #pragma unroll
                for (int i = 0; i < 2; ++i) {
                    int hy = r0 + i;
                    int gy = gy0 + hy - 2;
                    #pragma unroll
                    for (int j = 0; j < 3; ++j) {
                        int hx = c0 + j;
                        int gx = gx0 + hx - 2;
                        float v = a[i][j] + bias;
                        v = (v >= 0.f) ? v : 0.1f * v;
                        if (gy < 0 || gy >= HH || gx < 0 || gx >= WW) v = 0.f;
                        hs[cc][hy][hx] = v;
                    }
                }
            }
        }

        __syncthreads();   // hs ready

        // ---- conv2 accumulate ----
        #pragma unroll 1
        for (int cc = 0; cc < 2; ++cc) {
            const int ch = ph * 2 + cc;
            #pragma unroll
            for (int dy = 0; dy < 5; ++dy) {
                const float4* hp = (const float4*)&hs[cc][ly + dy][lx0];
                float4 ha = hp[0];
                float4 hb = hp[1];
                float hreg[8] = {ha.x, ha.y, ha.z, ha.w, hb.x, hb.y, hb.z, hb.w};
                #pragma unroll
                for (int f = 0; f < 9; ++f) {
                    const float* wp = w2 + (f * 32 + ch) * 25 + dy * 5;
                    #pragma unroll
                    for (int dx = 0; dx < 5; ++dx) {
                        float wv = wp[dx];
                        #pragma unroll
                        for (int p = 0; p < 4; ++p)
                            acc[f][p] += hreg[p + dx] * wv;
                    }
                }
            }
        }
    }

    // ---- epilogue: im2col(3x3, pad=1) dot; xs OOB entries are already 0 ----
    float res[4] = {0.f, 0.f, 0.f, 0.f};
    #pragma unroll
    for (int fy = 0; fy < 3; ++fy) {
        #pragma unroll
        for (int fx = 0; fx < 3; ++fx) {
            int f = fy * 3 + fx;
            float bf = b2[f];
            #pragma unroll
            for (int p = 0; p < 4; ++p) {
                float e = xs[0][ly + fy + 3][lx0 + p + fx + 3];
                res[p] += e * (acc[f][p] + bf);
            }
        }
    }

    size_t o = ((size_t)b * HH + (gy0 + ly)) * WW + gx0 + lx0;
    float4 ov = make_float4(res[0], res[1], res[2], res[3]);
    *(float4*)(out + o) = ov;
}

extern "C" void kernel_launch(void* const* d_in, const int* in_sizes, int n_in,
                              void* d_out, int out_size, void* d_ws, size_t ws_size,
                              hipStream_t stream) {
    const float* image = (const float*)d_in[0];
    const float* refer = (const float*)d_in[1];
    const float* w1    = (const float*)d_in[2];
    const float* b1    = (const float*)d_in[3];
    const float* w2    = (const float*)d_in[4];
    const float* b2    = (const float*)d_in[5];
    float* out = (float*)d_out;

    dim3 grid(WW / TILE, HH / TILE, 8);
    dim3 block(256);
    hipLaunchKernelGGL(dynfilt_fused, grid, block, 0, stream,
                       image, refer, w1, b1, w2, b2, out);
}

// Round 4
// 535.820 us; speedup vs baseline: 5.5826x; 2.4040x over previous
//
#include <hip/hip_runtime.h>

// DynamicFilter fused kernel (fp32, vector ALU).
// R4 change: bound weight-hoisting windows. R2/R3 spilled ~50 VGPRs/phase
// (WRITE_SIZE 1.67 GB, rewritten every phase) because the fully-unrolled
// conv2 body exposes 225 uniform weight values per cc-iteration -> SGPR
// overflow -> VGPR copies -> acc spill. Making dy (conv2) and ci (conv1)
// runtime loops caps live weights at 45 / 25, which fit in SGPRs; their
// addresses depend on the loop var so LICM can't re-hoist. waves_per_eu(4)
// targets 128-VGPR / 4 waves/SIMD occupancy.
//
// Pipeline per 32x32 output tile (one block, 256 threads):
//   1. Load x halo (2ch, 40x40, zero-filled OOB) into LDS.
//   2. 16 phases x 2 channels:
//        conv1 5x5 (2->ch) + bias + LeakyReLU on 36x36 halo -> LDS hs
//        (h forced to 0 outside global bounds == conv2 zero-padding)
//        conv2 5x5 accumulate into 9 filter accs x 4 px per thread.
//   3. Epilogue: out = sum_f image[y+fy-1][x+fx-1] * (acc[f]+b2[f]), float4 store.

#define HH 512
#define WW 512
#define TILE 32
#define XS_H 40
#define XS_W 40
#define HS_H 36
#define HS_W 40   // padded row stride, keeps 16B alignment for b128 reads

__global__
__attribute__((amdgpu_flat_work_group_size(256, 256), amdgpu_waves_per_eu(4)))
void dynfilt_fused(const float* __restrict__ image,
                   const float* __restrict__ refer,
                   const float* __restrict__ w1,
                   const float* __restrict__ b1,
                   const float* __restrict__ w2,
                   const float* __restrict__ b2,
                   float* __restrict__ out)
{
    __shared__ float xs[2][XS_H][XS_W];
    __shared__ float hs[2][HS_H][HS_W];

    const int t  = threadIdx.x;
    const int gx0 = blockIdx.x * TILE;
    const int gy0 = blockIdx.y * TILE;
    const int b   = blockIdx.z;

    // ---- stage x halo: rows gy0-4..gy0+35, cols gx0-4..gx0+35, 2 channels ----
    for (int idx = t; idx < 2 * XS_H * XS_W; idx += 256) {
        int ci  = idx / (XS_H * XS_W);
        int rem = idx - ci * (XS_H * XS_W);
        int r   = rem / XS_W;
        int c   = rem - r * XS_W;
        int gy  = gy0 - 4 + r;
        int gx  = gx0 - 4 + c;
        float v = 0.f;
        if (gy >= 0 && gy < HH && gx >= 0 && gx < WW) {
            const float* src = ci ? refer : image;
            v = src[((size_t)b * HH + gy) * WW + gx];
        }
        (&xs[0][0][0])[idx] = v;
    }

    // per-thread output pixels: row ly, cols lx0..lx0+3
    const int ly  = t >> 3;
    const int lx0 = (t & 7) << 2;

    // conv1 strip mapping: 216 slots, each computes 2 rows x 3 cols of h
    const int rp = t / 12;        // row pair 0..17
    const int cg = t - rp * 12;   // col group 0..11
    const int r0 = rp * 2;
    const int c0 = cg * 3;

    float acc[9][4];
    #pragma unroll
    for (int f = 0; f < 9; ++f)
        #pragma unroll
        for (int p = 0; p < 4; ++p)
            acc[f][p] = 0.f;

    #pragma unroll 1
    for (int ph = 0; ph < 16; ++ph) {
        __syncthreads();   // prev conv2 done reading hs (and xs load on ph=0)

        // ---- conv1: channels 2ph, 2ph+1 into hs[0], hs[1] ----
        if (t < 216) {
            #pragma unroll 1
            for (int cc = 0; cc < 2; ++cc) {
                const int ch = ph * 2 + cc;
                float a[2][3] = {{0.f,0.f,0.f},{0.f,0.f,0.f}};
                #pragma unroll 1
                for (int ci = 0; ci < 2; ++ci) {   // unroll 1: cap live weights at 25
                    const float* wp = w1 + (ch * 2 + ci) * 25;
                    #pragma unroll
                    for (int wy = 0; wy < 6; ++wy) {
                        float rv[7];
                        #pragma unroll
                        for (int j = 0; j < 7; ++j)
                            rv[j] = xs[ci][r0 + wy][c0 + j];
                        if (wy < 5) {
                            #pragma unroll
                            for (int dx = 0; dx < 5; ++dx) {
                                float wv = wp[wy * 5 + dx];
                                #pragma unroll
                                for (int j = 0; j < 3; ++j)
                                    a[0][j] += rv[j + dx] * wv;
                            }
                        }
                        if (wy >= 1) {
                            #pragma unroll
                            for (int dx = 0; dx < 5; ++dx) {
                                float wv = wp[(wy - 1) * 5 + dx];
                                #pragma unroll
                                for (int j = 0; j < 3; ++j)
                                    a[1][j] += rv[j + dx] * wv;
                            }
                        }
                    }
                }
                float bias = b1[ch];
                #pragma unroll
                for (int i = 0; i < 2; ++i) {
                    int hy = r0 + i;
                    int gy = gy0 + hy - 2;
                    #pragma unroll
                    for (int j = 0; j < 3; ++j) {
                        int hx = c0 + j;
                        int gx = gx0 + hx - 2;
                        float v = a[i][j] + bias;
                        v = (v >= 0.f) ? v : 0.1f * v;
                        if (gy < 0 || gy >= HH || gx < 0 || gx >= WW) v = 0.f;
                        hs[cc][hy][hx] = v;
                    }
                }
            }
        }

        __syncthreads();   // hs ready

        // ---- conv2 accumulate ----
        #pragma unroll 1
        for (int cc = 0; cc < 2; ++cc) {
            const int ch = ph * 2 + cc;
            #pragma unroll 1
            for (int dy = 0; dy < 5; ++dy) {   // unroll 1: cap live weights at 45
                const float4* hp = (const float4*)&hs[cc][ly + dy][lx0];
                float4 ha = hp[0];
                float4 hb = hp[1];
                float hreg[8] = {ha.x, ha.y, ha.z, ha.w, hb.x, hb.y, hb.z, hb.w};
                #pragma unroll
                for (int f = 0; f < 9; ++f) {
                    const float* wp = w2 + (f * 32 + ch) * 25 + dy * 5;
                    #pragma unroll
                    for (int dx = 0; dx < 5; ++dx) {
                        float wv = wp[dx];
                        #pragma unroll
                        for (int p = 0; p < 4; ++p)
                            acc[f][p] += hreg[p + dx] * wv;
                    }
                }
            }
        }
    }

    // ---- epilogue: im2col(3x3, pad=1) dot; xs OOB entries are already 0 ----
    float res[4] = {0.f, 0.f, 0.f, 0.f};
    #pragma unroll
    for (int fy = 0; fy < 3; ++fy) {
        #pragma unroll
        for (int fx = 0; fx < 3; ++fx) {
            int f = fy * 3 + fx;
            float bf = b2[f];
            #pragma unroll
            for (int p = 0; p < 4; ++p) {
                float e = xs[0][ly + fy + 3][lx0 + p + fx + 3];
                res[p] += e * (acc[f][p] + bf);
            }
        }
    }

    size_t o = ((size_t)b * HH + (gy0 + ly)) * WW + gx0 + lx0;
    float4 ov = make_float4(res[0], res[1], res[2], res[3]);
    *(float4*)(out + o) = ov;
}

extern "C" void kernel_launch(void* const* d_in, const int* in_sizes, int n_in,
                              void* d_out, int out_size, void* d_ws, size_t ws_size,
                              hipStream_t stream) {
    const float* image = (const float*)d_in[0];
    const float* refer = (const float*)d_in[1];
    const float* w1    = (const float*)d_in[2];
    const float* b1    = (const float*)d_in[3];
    const float* w2    = (const float*)d_in[4];
    const float* b2    = (const float*)d_in[5];
    float* out = (float*)d_out;

    dim3 grid(WW / TILE, HH / TILE, 8);
    dim3 block(256);
    hipLaunchKernelGGL(dynfilt_fused, grid, block, 0, stream,
                       image, refer, w1, b1, w2, b2, out);
}